// Round 5
// baseline (172.151 us; speedup 1.0000x reference)
//
#include <hip/hip_runtime.h>
#include <hip/hip_bf16.h>

#define BATCH 16
#define INP   128
#define OUP   128
#define HH    56
#define WW    56
#define HWSZ  3136     // 56*56
#define HID   768
#define KC    64
#define NCHUNK 12
#define TILY  4
#define TILX  14
#define NSLOT 96       // 6 halo rows x 16 halo cols
#define NOPX  56       // 4*14 output px
#define H1S   104      // h1 row stride (elems): 13 octets, 16B-aligned, 20-dw bank stagger
#define H2S   72       // h2 row stride: 9 octets, 16B-aligned
#define EPSV  1e-5f

typedef __attribute__((ext_vector_type(8))) short bf16x8;
typedef __attribute__((ext_vector_type(4))) float f32x4;

__device__ __forceinline__ unsigned short f2b(float f) {
    unsigned u = __float_as_uint(f);
    return (unsigned short)((u + 0x7FFFu + ((u >> 16) & 1u)) >> 16);   // RNE
}
__device__ __forceinline__ float blo(unsigned u){ return __uint_as_float(u << 16); }
__device__ __forceinline__ float bhi(unsigned u){ return __uint_as_float(u & 0xFFFF0000u); }
__device__ __forceinline__ unsigned pkbf(float lo, float hi) {
    unsigned r;
    asm("v_cvt_pk_bf16_f32 %0, %1, %2" : "=v"(r) : "v"(lo), "v"(hi));
    return r;
}

// ---------------- pre-kernel: fold BN into bf16 weights, once ----------------
__global__ void prep(const float* __restrict__ w1, const float* __restrict__ g1,
                     const float* __restrict__ b1, const float* __restrict__ m1, const float* __restrict__ v1,
                     const float* __restrict__ wdw, const float* __restrict__ g2,
                     const float* __restrict__ b2, const float* __restrict__ m2, const float* __restrict__ v2,
                     const float* __restrict__ w2, const float* __restrict__ g3,
                     const float* __restrict__ b3, const float* __restrict__ m3, const float* __restrict__ v3,
                     unsigned short* __restrict__ w1b, unsigned short* __restrict__ w2b,
                     float* __restrict__ be1o, float* __restrict__ wdsf,
                     float* __restrict__ be2o, float* __restrict__ be3o)
{
    int gid = blockIdx.x * blockDim.x + threadIdx.x;
    int stp = gridDim.x * blockDim.x;
    for (int i = gid; i < HID * INP; i += stp) {
        int r = i >> 7;
        float s = g1[r] * rsqrtf(v1[r] + EPSV);
        w1b[i] = f2b(w1[i] * s);
    }
    for (int i = gid; i < OUP * HID; i += stp) {
        int r = i / HID;
        float s = g3[r] * rsqrtf(v3[r] + EPSV);
        w2b[i] = f2b(w2[i] * s);
    }
    for (int i = gid; i < HID; i += stp) {
        float s1 = g1[i] * rsqrtf(v1[i] + EPSV);
        be1o[i] = b1[i] - m1[i] * s1;
        float s2 = g2[i] * rsqrtf(v2[i] + EPSV);
        be2o[i] = b2[i] - m2[i] * s2;
    }
    for (int i = gid; i < HID * 9; i += stp) {          // tap-major: wdsf[q][c]
        int q = i / HID, c = i - q * HID;
        float s2 = g2[c] * rsqrtf(v2[c] + EPSV);
        wdsf[i] = wdw[c * 9 + q] * s2;
    }
    for (int i = gid; i < OUP; i += stp) {
        float s3 = g3[i] * rsqrtf(v3[i] + EPSV);
        be3o[i] = b3[i] - m3[i] * s3;
    }
}

// ---------------- fused main kernel: tile 4x14, 3 blocks/CU ----------------
__launch_bounds__(256, 3)
__global__ void fused_ir(const float* __restrict__ x,
                         const unsigned short* __restrict__ w1b,
                         const unsigned short* __restrict__ w2b,
                         const float* __restrict__ be1g,
                         const float* __restrict__ wdsf,
                         const float* __restrict__ be2g,
                         const float* __restrict__ be3g,
                         const int* __restrict__ mask,
                         float* __restrict__ out)
{
    __shared__ unsigned short xs[NSLOT * 128];   // 24576 B  bf16 x halo [slot][c], octet-swizzled
    __shared__ unsigned short h1t[KC * H1S];     // 13312 B  bf16 h1 [c][slot]
    __shared__ unsigned short h2s[64 * H2S];     //  9216 B  bf16 h2 [px][c] (px 56..63 zero pad)
    __shared__ float mdv[NSLOT];                 //   384 B  dilated mask at halo slots
    __shared__ float mfv_[NOPX];                 //   224 B  mask at output px
    __shared__ float mtmp[8 * 18];               //   576 B  mask staging
    // total 48288 B -> 3 blocks/CU

    const int t    = threadIdx.x;
    const int b    = blockIdx.y;
    const int tile = blockIdx.x;
    const int h0   = (tile >> 2) * TILY;         // 14 y-tiles
    const int w0   = (tile & 3) * TILX;          // 4 x-tiles
    const int lane = t & 63;
    const int wv   = t >> 6;                     // wave 0..3
    const int g    = lane >> 4;                  // k-octet / px-quad group
    const int r16  = lane & 15;

    // ---------------- prologue: stage mask + x halo ----------------
    for (int i = t; i < 144; i += 256) {         // 8 rows x 18 cols, rows h0-2..h0+5
        int r = (i * 57) >> 10;                  // i/18
        int cc = i - r * 18;
        int gy = h0 + r - 2, gx = w0 + cc - 2;
        float v = 0.f;
        if (gy >= 0 && gy < HH && gx >= 0 && gx < WW)
            v = (float)mask[(b * HH + gy) * WW + gx];
        mtmp[i] = v;
    }
    for (int i = t; i < (64 - NOPX) * H2S; i += 256)   // zero h2 pad rows once
        h2s[NOPX * H2S + i] = 0;
    // x halo: 96 slots x 128 ch, [slot][c] bf16 swizzled
    {
        const int tc = t >> 5, tx32 = t & 31;
        for (int c4 = tc; c4 < 32; c4 += 8) {
            for (int sb = 0; sb < NSLOT; sb += 32) {
                int slot = sb + tx32;
                int hy = slot >> 4, hx = slot & 15;
                int gy = h0 + hy - 1, gx = w0 + hx - 1;
                ushort4 u; u.x = 0; u.y = 0; u.z = 0; u.w = 0;
                if (gy >= 0 && gy < HH && gx >= 0 && gx < WW) {
                    const float* xp = x + (((size_t)b * INP + c4 * 4) * HH + gy) * WW + gx;
                    float a0 = xp[0], a1 = xp[HWSZ], a2 = xp[2 * HWSZ], a3 = xp[3 * HWSZ];
                    unsigned p0 = pkbf(a0, a1), p1 = pkbf(a2, a3);
                    u.x = (unsigned short)p0; u.y = (unsigned short)(p0 >> 16);
                    u.z = (unsigned short)p1; u.w = (unsigned short)(p1 >> 16);
                }
                int el = slot * 128 + ((((c4 >> 1) ^ (slot & 15))) << 3) + ((c4 & 1) << 2);
                *(ushort4*)&xs[el] = u;
            }
        }
    }
    __syncthreads();
    // dilated mask at halo slots; mask at output px
    if (t < NSLOT) {
        int hy = t >> 4, hx = t & 15;
        int gy = h0 + hy - 1, gx = w0 + hx - 1;
        float mm = 0.f;
        #pragma unroll
        for (int dy = 0; dy < 3; ++dy)
            #pragma unroll
            for (int dx = 0; dx < 3; ++dx)
                mm = fmaxf(mm, mtmp[(hy + dy) * 18 + hx + dx]);
        if (gy < 0 || gy >= HH || gx < 0 || gx >= WW) mm = 0.f;
        mdv[t] = mm;
    }
    if (t < NOPX) {
        int iy = (t * 2341) >> 15;               // t/14
        int ix = t - iy * 14;
        mfv_[t] = mtmp[(iy + 2) * 18 + ix + 2];
    }
    __syncthreads();

    // project accumulators: wave wv -> out-ch tiles {2wv, 2wv+1}, all 4 n-tiles
    f32x4 pacc[2][4];
    #pragma unroll
    for (int ot = 0; ot < 2; ++ot)
        #pragma unroll
        for (int nt = 0; nt < 4; ++nt) {
            pacc[ot][nt][0] = 0.f; pacc[ot][nt][1] = 0.f;
            pacc[ot][nt][2] = 0.f; pacc[ot][nt][3] = 0.f;
        }

    // ---- phase E: expand MFMA for chunk ch (writes h1) ----
    auto phaseE = [&](int ch) {
        const int k0 = ch * KC;
        float be1r[4];
        #pragma unroll
        for (int mt = 0; mt < 4; ++mt) be1r[mt] = be1g[k0 + mt * 16 + r16];
        for (int nt = wv; nt < 6; nt += 4) {     // waves 0,1: 2 tiles; waves 2,3: 1
            const int px = nt * 16 + r16;
            f32x4 eacc[4];
            #pragma unroll
            for (int mt = 0; mt < 4; ++mt) {
                eacc[mt][0] = 0.f; eacc[mt][1] = 0.f; eacc[mt][2] = 0.f; eacc[mt][3] = 0.f;
            }
            #pragma unroll
            for (int ks = 0; ks < 4; ++ks) {
                const bf16x8 af = *(const bf16x8*)&xs[px * 128 + (((ks * 4 + g) ^ r16) << 3)];
                #pragma unroll
                for (int mt = 0; mt < 4; ++mt) {
                    const bf16x8 wf = *(const bf16x8*)&w1b[(size_t)(k0 + mt * 16 + r16) * INP + ks * 32 + g * 8];
                    eacc[mt] = __builtin_amdgcn_mfma_f32_16x16x32_bf16(af, wf, eacc[mt], 0, 0, 0);
                }
            }
            const int px4 = nt * 16 + g * 4;
            const float4 md4 = *(const float4*)&mdv[px4];
            #pragma unroll
            for (int mt = 0; mt < 4; ++mt) {
                const int c = mt * 16 + r16;
                const float be = be1r[mt];
                float v0 = fminf(fmaxf(eacc[mt][0] + be, 0.f), 6.f) * md4.x;
                float v1 = fminf(fmaxf(eacc[mt][1] + be, 0.f), 6.f) * md4.y;
                float v2 = fminf(fmaxf(eacc[mt][2] + be, 0.f), 6.f) * md4.z;
                float v3 = fminf(fmaxf(eacc[mt][3] + be, 0.f), 6.f) * md4.w;
                uint2 pk; pk.x = pkbf(v0, v1); pk.y = pkbf(v2, v3);
                *(uint2*)&h1t[c * H1S + px4] = pk;
            }
        }
    };

    // ---- phase D: depthwise 3x3 + BN2 + relu6 + mf (reads h1, writes h2) ----
    auto phaseD = [&](int ch) {
        const int k0 = ch * KC;
        const int c = t & 63, y = t >> 6;        // y wave-uniform
        float wt[9];
        #pragma unroll
        for (int q = 0; q < 9; ++q) wt[q] = wdsf[q * HID + k0 + c];
        const float be = be2g[k0 + c];
        float rr[3][16];
        #pragma unroll
        for (int dy = 0; dy < 3; ++dy) {
            const unsigned short* hp = &h1t[c * H1S + (y + dy) * 16];
            const uint4 q0 = *(const uint4*)hp;
            const uint4 q1 = *(const uint4*)(hp + 8);
            rr[dy][0] = blo(q0.x);  rr[dy][1] = bhi(q0.x);
            rr[dy][2] = blo(q0.y);  rr[dy][3] = bhi(q0.y);
            rr[dy][4] = blo(q0.z);  rr[dy][5] = bhi(q0.z);
            rr[dy][6] = blo(q0.w);  rr[dy][7] = bhi(q0.w);
            rr[dy][8] = blo(q1.x);  rr[dy][9] = bhi(q1.x);
            rr[dy][10] = blo(q1.y); rr[dy][11] = bhi(q1.y);
            rr[dy][12] = blo(q1.z); rr[dy][13] = bhi(q1.z);
            rr[dy][14] = blo(q1.w); rr[dy][15] = bhi(q1.w);
        }
        #pragma unroll
        for (int xx = 0; xx < 14; ++xx) {
            const float mv = mfv_[y * 14 + xx];  // wave-uniform -> real branch skip
            unsigned u = 0;
            if (mv != 0.f) {
                float s = rr[0][xx] * wt[0] + rr[0][xx + 1] * wt[1] + rr[0][xx + 2] * wt[2]
                        + rr[1][xx] * wt[3] + rr[1][xx + 1] * wt[4] + rr[1][xx + 2] * wt[5]
                        + rr[2][xx] * wt[6] + rr[2][xx + 1] * wt[7] + rr[2][xx + 2] * wt[8];
                float v = fminf(fmaxf(s + be, 0.f), 6.f);
                u = pkbf(v, v);                  // low 16 bits = bf16 RNE
            }
            h2s[(y * 14 + xx) * H2S + c] = (unsigned short)u;
        }
    };

    // ---- phase P: project MFMA accumulate (reads h2) ----
    auto phaseP = [&](int ch) {
        const int k0 = ch * KC;
        #pragma unroll
        for (int ks = 0; ks < 2; ++ks) {
            bf16x8 pw[2];
            #pragma unroll
            for (int ot = 0; ot < 2; ++ot)
                pw[ot] = *(const bf16x8*)&w2b[(size_t)((wv * 2 + ot) * 16 + r16) * HID + k0 + ks * 32 + g * 8];
            #pragma unroll
            for (int nt = 0; nt < 4; ++nt) {
                const bf16x8 hb = *(const bf16x8*)&h2s[(nt * 16 + r16) * H2S + (ks * 4 + g) * 8];
                #pragma unroll
                for (int ot = 0; ot < 2; ++ot)
                    pacc[ot][nt] = __builtin_amdgcn_mfma_f32_16x16x32_bf16(pw[ot], hb, pacc[ot][nt], 0, 0, 0);
            }
        }
    };

    // ---- main loop: E | bar | D | bar | P + E(next) | bar ----
    phaseE(0);
    __syncthreads();
    for (int ch = 0; ch < NCHUNK; ++ch) {
        phaseD(ch);
        __syncthreads();
        phaseP(ch);
        if (ch + 1 < NCHUNK) phaseE(ch + 1);
        __syncthreads();
    }

    // ---------------- epilogue: out = x + (proj + be3) * mf ----------------
    #pragma unroll
    for (int ot = 0; ot < 2; ++ot) {
        const int ob = (wv * 2 + ot) * 16 + g * 4;
        const float4 be4 = *(const float4*)&be3g[ob];
        #pragma unroll
        for (int nt = 0; nt < 4; ++nt) {
            const int px = nt * 16 + r16;
            if (px < NOPX) {
                const int iy = (px * 2341) >> 15;     // px/14
                const int ix = px - iy * 14;
                const int gy = h0 + iy, gx = w0 + ix;
                const float mv = mfv_[px];
                const size_t base = (((size_t)b * OUP + ob) * HH + gy) * WW + gx;
                out[base]            = x[base]            + (pacc[ot][nt][0] + be4.x) * mv;
                out[base + HWSZ]     = x[base + HWSZ]     + (pacc[ot][nt][1] + be4.y) * mv;
                out[base + 2 * HWSZ] = x[base + 2 * HWSZ] + (pacc[ot][nt][2] + be4.z) * mv;
                out[base + 3 * HWSZ] = x[base + 3 * HWSZ] + (pacc[ot][nt][3] + be4.w) * mv;
            }
        }
    }
}

extern "C" void kernel_launch(void* const* d_in, const int* in_sizes, int n_in,
                              void* d_out, int out_size, void* d_ws, size_t ws_size,
                              hipStream_t stream) {
    (void)in_sizes; (void)n_in; (void)out_size; (void)ws_size;
    const float* x   = (const float*)d_in[0];
    const float* w1  = (const float*)d_in[1];
    const float* g1  = (const float*)d_in[2];
    const float* b1  = (const float*)d_in[3];
    const float* m1  = (const float*)d_in[4];
    const float* v1  = (const float*)d_in[5];
    const float* wdw = (const float*)d_in[6];
    const float* g2  = (const float*)d_in[7];
    const float* b2  = (const float*)d_in[8];
    const float* m2  = (const float*)d_in[9];
    const float* v2  = (const float*)d_in[10];
    const float* w2  = (const float*)d_in[11];
    const float* g3  = (const float*)d_in[12];
    const float* b3  = (const float*)d_in[13];
    const float* m3  = (const float*)d_in[14];
    const float* v3  = (const float*)d_in[15];
    const int*  mask = (const int*)d_in[16];
    float* out = (float*)d_out;

    char* ws = (char*)d_ws;
    unsigned short* w1b = (unsigned short*)ws;                 // 196608 B
    unsigned short* w2b = (unsigned short*)(ws + 196608);      // 196608 B
    float* be1o = (float*)(ws + 393216);                       // 3072 B
    float* wdsf = (float*)(ws + 396288);                       // 27648 B  [9][768]
    float* be2o = (float*)(ws + 423936);                       // 3072 B
    float* be3o = (float*)(ws + 427008);                       // 512 B

    prep<<<128, 256, 0, stream>>>(w1, g1, b1, m1, v1, wdw, g2, b2, m2, v2,
                                  w2, g3, b3, m3, v3, w1b, w2b, be1o, wdsf, be2o, be3o);
    // 14 y-tiles x 4 x-tiles = 56 tiles/image, 16 images -> 896 blocks
    fused_ir<<<dim3(56, BATCH), 256, 0, stream>>>(x, w1b, w2b, be1o, wdsf, be2o, be3o, mask, out);
}

// Round 6
// 129.820 us; speedup vs baseline: 1.3261x; 1.3261x over previous
//
#include <hip/hip_runtime.h>
#include <hip/hip_bf16.h>

#define BATCH 16
#define INP   128
#define OUP   128
#define HH    56
#define WW    56
#define HWSZ  3136
#define HID   768
#define EPSV  1e-5f

typedef __attribute__((ext_vector_type(8))) short bf16x8;
typedef __attribute__((ext_vector_type(4))) float f32x4;

__device__ __forceinline__ unsigned short f2b(float f) {
    unsigned u = __float_as_uint(f);
    return (unsigned short)((u + 0x7FFFu + ((u >> 16) & 1u)) >> 16);   // RNE
}
__device__ __forceinline__ float blo(unsigned u){ return __uint_as_float(u << 16); }
__device__ __forceinline__ float bhi(unsigned u){ return __uint_as_float(u & 0xFFFF0000u); }
__device__ __forceinline__ unsigned pkbf(float lo, float hi) {
    unsigned r;
    asm("v_cvt_pk_bf16_f32 %0, %1, %2" : "=v"(r) : "v"(lo), "v"(hi));
    return r;
}

// ---------------- prep: fold BN into bf16 weights + mask dilate, once ----------------
__global__ void prep(const float* __restrict__ w1, const float* __restrict__ g1,
                     const float* __restrict__ b1, const float* __restrict__ m1, const float* __restrict__ v1,
                     const float* __restrict__ wdw, const float* __restrict__ g2,
                     const float* __restrict__ b2, const float* __restrict__ m2, const float* __restrict__ v2,
                     const float* __restrict__ w2, const float* __restrict__ g3,
                     const float* __restrict__ b3, const float* __restrict__ m3, const float* __restrict__ v3,
                     const int* __restrict__ mask,
                     unsigned short* __restrict__ w1b, unsigned short* __restrict__ w2b,
                     float* __restrict__ be1o, float* __restrict__ wdsf,
                     float* __restrict__ be2o, float* __restrict__ be3o,
                     float* __restrict__ mdf, float* __restrict__ mff)
{
    int gid = blockIdx.x * blockDim.x + threadIdx.x;
    int stp = gridDim.x * blockDim.x;
    for (int i = gid; i < HID * INP; i += stp) {
        int r = i >> 7;
        float s = g1[r] * rsqrtf(v1[r] + EPSV);
        w1b[i] = f2b(w1[i] * s);
    }
    for (int i = gid; i < OUP * HID; i += stp) {
        int r = i / HID;
        float s = g3[r] * rsqrtf(v3[r] + EPSV);
        w2b[i] = f2b(w2[i] * s);
    }
    for (int i = gid; i < HID; i += stp) {
        float s1 = g1[i] * rsqrtf(v1[i] + EPSV);
        be1o[i] = b1[i] - m1[i] * s1;
        float s2 = g2[i] * rsqrtf(v2[i] + EPSV);
        be2o[i] = b2[i] - m2[i] * s2;
    }
    for (int i = gid; i < HID * 9; i += stp) {          // tap-major [q][c], BN2 scale folded
        int q = i / HID, c = i - q * HID;
        float s2 = g2[c] * rsqrtf(v2[c] + EPSV);
        wdsf[i] = wdw[c * 9 + q] * s2;
    }
    for (int i = gid; i < OUP; i += stp) {
        float s3 = g3[i] * rsqrtf(v3[i] + EPSV);
        be3o[i] = b3[i] - m3[i] * s3;
    }
    for (int i = gid; i < BATCH * HWSZ; i += stp) {     // mf + 3x3 dilated md
        int b = i / HWSZ, p = i - b * HWSZ;
        int y = p / WW, xx = p - y * WW;
        float mf = (float)mask[i];
        float md = 0.f;
        for (int dy = -1; dy <= 1; ++dy)
            for (int dx = -1; dx <= 1; ++dx) {
                int yy = y + dy, xc = xx + dx;
                if (yy >= 0 && yy < HH && xc >= 0 && xc < WW)
                    md = fmaxf(md, (float)mask[b * HWSZ + yy * WW + xc]);
            }
        mff[i] = mf;
        mdf[i] = md;
    }
}

// ---------------- K1: expand GEMM -> h1 (bf16 pair-interleaved [b][c/2][p][2]) ----------------
__launch_bounds__(256, 3)
__global__ void k1_expand(const float* __restrict__ x,
                          const unsigned short* __restrict__ w1b,
                          const float* __restrict__ be1g,
                          const float* __restrict__ mdf,
                          unsigned* __restrict__ h1p)
{
    __shared__ unsigned short xs[128 * 128];   // 32 KB  bf16 x-tile [px][c] swizzled
    const int t = threadIdx.x, lane = t & 63, wv = t >> 6;
    const int g = lane >> 4, r16 = lane & 15;
    const int pb = blockIdx.x, hb = blockIdx.y, b = blockIdx.z;
    const int p0 = pb * 128;
    const int whid = wv & 1, wpx = wv >> 1;

    // stage x tile (fp32 -> bf16), coalesced along p
    for (int rep = 0; rep < 16; ++rep) {
        int id = t + rep * 256;
        int px = id & 127, c4 = id >> 7;       // c4: 4-channel group 0..31
        int p = p0 + px;
        ushort4 u; u.x = 0; u.y = 0; u.z = 0; u.w = 0;
        if (p < HWSZ) {
            const float* xp = x + ((size_t)(b * INP + c4 * 4)) * HWSZ + p;
            unsigned lo = pkbf(xp[0], xp[HWSZ]);
            unsigned hi = pkbf(xp[2 * HWSZ], xp[3 * HWSZ]);
            u.x = (unsigned short)lo; u.y = (unsigned short)(lo >> 16);
            u.z = (unsigned short)hi; u.w = (unsigned short)(hi >> 16);
        }
        *(ushort4*)&xs[px * 128 + (((c4 >> 1) ^ (px & 15)) << 3) + ((c4 & 1) << 2)] = u;
    }
    __syncthreads();

    f32x4 acc[4][4];
    #pragma unroll
    for (int mt = 0; mt < 4; ++mt)
        #pragma unroll
        for (int nt = 0; nt < 4; ++nt) {
            acc[mt][nt][0] = 0.f; acc[mt][nt][1] = 0.f;
            acc[mt][nt][2] = 0.f; acc[mt][nt][3] = 0.f;
        }
    const int hbase = hb * 128 + whid * 64;

    #pragma unroll
    for (int ks = 0; ks < 4; ++ks) {
        bf16x8 af[4];
        #pragma unroll
        for (int mt = 0; mt < 4; ++mt)
            af[mt] = *(const bf16x8*)&w1b[(size_t)(hbase + mt * 16 + r16) * INP + ks * 32 + g * 8];
        #pragma unroll
        for (int nt = 0; nt < 4; ++nt) {
            int px = wpx * 64 + nt * 16 + r16;
            bf16x8 bf = *(const bf16x8*)&xs[px * 128 + (((ks * 4 + g) ^ r16) << 3)];
            #pragma unroll
            for (int mt = 0; mt < 4; ++mt)
                acc[mt][nt] = __builtin_amdgcn_mfma_f32_16x16x32_bf16(af[mt], bf, acc[mt][nt], 0, 0, 0);
        }
    }

    // epilogue: BN1 bias + relu6 + md, pack hid-pairs, coalesced dword stores
    #pragma unroll
    for (int nt = 0; nt < 4; ++nt) {
        const int pg = p0 + wpx * 64 + nt * 16;
        if (pg >= HWSZ) continue;              // wave-uniform
        const int p = pg + r16;
        const float md = mdf[b * HWSZ + p];
        #pragma unroll
        for (int mt = 0; mt < 4; ++mt) {
            const float4 be4 = *(const float4*)&be1g[hbase + mt * 16 + g * 4];
            f32x4 a = acc[mt][nt];
            float v0 = fminf(fmaxf(a[0] + be4.x, 0.f), 6.f) * md;
            float v1 = fminf(fmaxf(a[1] + be4.y, 0.f), 6.f) * md;
            float v2 = fminf(fmaxf(a[2] + be4.z, 0.f), 6.f) * md;
            float v3 = fminf(fmaxf(a[3] + be4.w, 0.f), 6.f) * md;
            const int c2 = (hbase >> 1) + mt * 8 + g * 2;
            const size_t ad = (size_t)(b * 384 + c2) * HWSZ + p;
            h1p[ad] = pkbf(v0, v1);
            h1p[ad + HWSZ] = pkbf(v2, v3);
        }
    }
}

// ---------------- K23: depthwise + project per 2-row strip ----------------
#define SCP 245   // stg per-channel-pair stride (dwords): 4 rows x 60 + 5 (odd mod 32)

__launch_bounds__(256, 2)
__global__ void k23(const unsigned* __restrict__ h1p,
                    const unsigned short* __restrict__ w2b,
                    const float* __restrict__ wdsf,
                    const float* __restrict__ be2g,
                    const float* __restrict__ be3g,
                    const float* __restrict__ mff,
                    const float* __restrict__ x,
                    float* __restrict__ out)
{
    __shared__ unsigned stg[2][32 * SCP];        // 62720 B  h1 rows [cp][4 rows x 60dw]
    __shared__ unsigned short h2s[112 * 72];     // 16128 B  h2 [px][c] swizzled
    __shared__ float mfv_[112];

    const int t = threadIdx.x, lane = t & 63, wv = t >> 6;
    const int g = lane >> 4, r16 = lane & 15;
    const int strip = blockIdx.x, b = blockIdx.y;
    const int y0 = strip * 2, p0 = strip * 112;

    if (t < 112) mfv_[t] = mff[b * HWSZ + p0 + t];
    {   // zero row pads (dwords 0,1,58,59 of each row, both buffers)
        int cp = t & 31, row = (t >> 5) & 3, buf = t >> 7;
        unsigned* s = &stg[buf][cp * SCP + row * 60];
        s[0] = 0; s[1] = 0; s[58] = 0; s[59] = 0;
    }

    auto stage = [&](int ch) {
        unsigned* sb = stg[ch & 1];
        #pragma unroll
        for (int rep = 0; rep < 7; ++rep) {
            int id = t + rep * 256;              // 1792 tasks: (cp, row, px4)
            int px4 = id % 14, rr = id / 14;
            int row = rr & 3, cp = rr >> 2;
            int gy = y0 - 1 + row;
            uint4 u; u.x = 0; u.y = 0; u.z = 0; u.w = 0;
            if (gy >= 0 && gy < HH)
                u = *(const uint4*)&h1p[(size_t)(b * 384 + ch * 32 + cp) * HWSZ + gy * WW + px4 * 4];
            unsigned* s = &sb[cp * SCP + row * 60 + 2 + px4 * 4];
            s[0] = u.x; s[1] = u.y; s[2] = u.z; s[3] = u.w;
        }
    };

    stage(0);
    __syncthreads();

    f32x4 pacc[2][7];
    #pragma unroll
    for (int ot = 0; ot < 2; ++ot)
        #pragma unroll
        for (int nt = 0; nt < 7; ++nt) {
            pacc[ot][nt][0] = 0.f; pacc[ot][nt][1] = 0.f;
            pacc[ot][nt][2] = 0.f; pacc[ot][nt][3] = 0.f;
        }

    for (int ch = 0; ch < 12; ++ch) {
        // ---- depthwise: thread = (cp 32, yy 2, k 4); 14 px x 2 ch each ----
        {
            const int cp = t & 31, yy = (t >> 5) & 1, k = t >> 6;
            const unsigned* sg = &stg[ch & 1][cp * SCP];
            float wlo[9], whi[9];
            #pragma unroll
            for (int q = 0; q < 9; ++q) {
                wlo[q] = wdsf[q * HID + ch * 64 + 2 * cp];
                whi[q] = wdsf[q * HID + ch * 64 + 2 * cp + 1];
            }
            const float belo = be2g[ch * 64 + 2 * cp];
            const float behi = be2g[ch * 64 + 2 * cp + 1];
            float acl[14], ach[14];
            #pragma unroll
            for (int j = 0; j < 14; ++j) { acl[j] = belo; ach[j] = behi; }
            #pragma unroll
            for (int dy = 0; dy < 3; ++dy) {
                float fl[16], fh[16];
                #pragma unroll
                for (int xx = 0; xx < 16; ++xx) {
                    unsigned uu = sg[(yy + dy) * 60 + 1 + 14 * k + xx];
                    fl[xx] = blo(uu); fh[xx] = bhi(uu);
                }
                #pragma unroll
                for (int j = 0; j < 14; ++j)
                    #pragma unroll
                    for (int dx = 0; dx < 3; ++dx) {
                        acl[j] += fl[j + dx] * wlo[dy * 3 + dx];
                        ach[j] += fh[j + dx] * whi[dy * 3 + dx];
                    }
            }
            unsigned* h2d = (unsigned*)h2s;
            #pragma unroll
            for (int j = 0; j < 14; ++j) {
                const int px = yy * 56 + k * 14 + j;
                const float mv = mfv_[px];
                float vlo = fminf(fmaxf(acl[j], 0.f), 6.f) * mv;
                float vhi = fminf(fmaxf(ach[j], 0.f), 6.f) * mv;
                h2d[px * 36 + (((cp >> 2) ^ (px & 7)) << 2) + (cp & 3)] = pkbf(vlo, vhi);
            }
        }
        __syncthreads();
        if (ch < 11) stage(ch + 1);              // prefetch next chunk under P
        // ---- project MFMA accumulate ----
        #pragma unroll
        for (int ks = 0; ks < 2; ++ks) {
            bf16x8 pw[2];
            #pragma unroll
            for (int ot = 0; ot < 2; ++ot)
                pw[ot] = *(const bf16x8*)&w2b[(size_t)((wv * 2 + ot) * 16 + r16) * HID + ch * 64 + ks * 32 + g * 8];
            #pragma unroll
            for (int nt = 0; nt < 7; ++nt) {
                const int px = nt * 16 + r16;
                const bf16x8 hb = *(const bf16x8*)&h2s[px * 72 + (((ks * 4 + g) ^ (px & 7)) << 3)];
                #pragma unroll
                for (int ot = 0; ot < 2; ++ot)
                    pacc[ot][nt] = __builtin_amdgcn_mfma_f32_16x16x32_bf16(pw[ot], hb, pacc[ot][nt], 0, 0, 0);
            }
        }
        __syncthreads();
    }

    // ---- epilogue: out = x + (proj + be3) * mf ----
    #pragma unroll
    for (int ot = 0; ot < 2; ++ot) {
        const int ob = (wv * 2 + ot) * 16 + g * 4;
        const float4 be4 = *(const float4*)&be3g[ob];
        #pragma unroll
        for (int nt = 0; nt < 7; ++nt) {
            const int px = nt * 16 + r16;
            const float mv = mfv_[px];
            const size_t base = (size_t)(b * OUP + ob) * HWSZ + p0 + px;
            out[base]            = x[base]            + (pacc[ot][nt][0] + be4.x) * mv;
            out[base + HWSZ]     = x[base + HWSZ]     + (pacc[ot][nt][1] + be4.y) * mv;
            out[base + 2 * HWSZ] = x[base + 2 * HWSZ] + (pacc[ot][nt][2] + be4.z) * mv;
            out[base + 3 * HWSZ] = x[base + 3 * HWSZ] + (pacc[ot][nt][3] + be4.w) * mv;
        }
    }
}

extern "C" void kernel_launch(void* const* d_in, const int* in_sizes, int n_in,
                              void* d_out, int out_size, void* d_ws, size_t ws_size,
                              hipStream_t stream) {
    (void)in_sizes; (void)n_in; (void)out_size; (void)ws_size;
    const float* x   = (const float*)d_in[0];
    const float* w1  = (const float*)d_in[1];
    const float* g1  = (const float*)d_in[2];
    const float* b1  = (const float*)d_in[3];
    const float* m1  = (const float*)d_in[4];
    const float* v1  = (const float*)d_in[5];
    const float* wdw = (const float*)d_in[6];
    const float* g2  = (const float*)d_in[7];
    const float* b2  = (const float*)d_in[8];
    const float* m2  = (const float*)d_in[9];
    const float* v2  = (const float*)d_in[10];
    const float* w2  = (const float*)d_in[11];
    const float* g3  = (const float*)d_in[12];
    const float* b3  = (const float*)d_in[13];
    const float* m3  = (const float*)d_in[14];
    const float* v3  = (const float*)d_in[15];
    const int*  mask = (const int*)d_in[16];
    float* out = (float*)d_out;

    char* ws = (char*)d_ws;
    unsigned short* w1b = (unsigned short*)ws;                 // 196608 B
    unsigned short* w2b = (unsigned short*)(ws + 196608);      // 196608 B
    float* be1o = (float*)(ws + 393216);                       // 3072 B
    float* wdsf = (float*)(ws + 396288);                       // 27648 B  [9][768]
    float* be2o = (float*)(ws + 423936);                       // 3072 B
    float* be3o = (float*)(ws + 427008);                       // 512 B
    float* mdf  = (float*)(ws + 427520);                       // 200704 B
    float* mff  = (float*)(ws + 628224);                       // 200704 B
    unsigned* h1p = (unsigned*)(ws + 828928);                  // 77070336 B (bf16 pairs)

    prep<<<256, 256, 0, stream>>>(w1, g1, b1, m1, v1, wdw, g2, b2, m2, v2,
                                  w2, g3, b3, m3, v3, mask,
                                  w1b, w2b, be1o, wdsf, be2o, be3o, mdf, mff);
    // K1: 25 px-blocks x 6 hid-blocks x 16 batches
    k1_expand<<<dim3(25, 6, 16), 256, 0, stream>>>(x, w1b, be1o, mdf, h1p);
    // K23: 28 strips x 16 batches
    k23<<<dim3(28, 16), 256, 0, stream>>>(h1p, w2b, wdsf, be2o, be3o, mff, x, out);
}